// Round 1
// 125.714 us; speedup vs baseline: 1.0049x; 1.0049x over previous
//
#include <hip/hip_runtime.h>
#include <stdint.h>

#define NB 8
#define CIN 64
#define COUT 64
#define HH 128
#define WW 128

typedef unsigned short ushort_t;
typedef unsigned int uint_t;
typedef __attribute__((ext_vector_type(8))) __bf16 bf16x8;
typedef __attribute__((ext_vector_type(4))) float f32x4;

__device__ __forceinline__ ushort_t f2bf(float f) {
  uint_t u = __builtin_bit_cast(uint_t, f);
  u += 0x7fffu + ((u >> 16) & 1u);
  return (ushort_t)(u >> 16);
}

// workspace layout (bytes)
#define WS_XSUM 0                 // 512 floats (B*CIN)
#define WS_XT   2048              // 8*128*128*64 bf16 = 16777216 B
#define WS_A    16779264          // 8*64*576 bf16 = 589824 B (16B aligned)

__global__ void k_zero(float* p) {
  int i = blockIdx.x * 256 + threadIdx.x;
  if (i < 512) p[i] = 0.f;
}

// Transpose x (B,C,H,W) f32 -> xT (B,H,W,C) bf16, fused per-(b,c) spatial sum.
__global__ void k_trans(const float* __restrict__ x, ushort_t* __restrict__ xT,
                        float* __restrict__ xsum) {
  __shared__ float tile[64 * 129];  // +1 pad: conflict-free column reads
  __shared__ float red[256];
  int b = blockIdx.x >> 7;
  int h = blockIdx.x & 127;
  int tid = threadIdx.x;
  int w = tid & 127;
  int ch = tid >> 7;  // 0..1
  const float* xp = x + ((size_t)(b * 64) * 128 + h) * 128 + w;
#pragma unroll
  for (int p = 0; p < 32; ++p) {
    int c = p * 2 + ch;
    tile[c * 129 + w] = xp[(size_t)c * 16384];
  }
  __syncthreads();
  // parallel partial sums: thread t sums 32 elems of row (t>>2)
  {
    int c = tid >> 2;
    int w4 = (tid & 3) * 32;
    float s = 0.f;
#pragma unroll
    for (int w2 = 0; w2 < 32; ++w2) s += tile[c * 129 + w4 + w2];
    red[tid] = s;
  }
  __syncthreads();
  if (tid < 64) {
    float s = red[tid * 4] + red[tid * 4 + 1] + red[tid * 4 + 2] + red[tid * 4 + 3];
    atomicAdd(&xsum[b * 64 + tid], s);
  }
#pragma unroll
  for (int it = 0; it < 4; ++it) {
    int chunk = tid + it * 256;  // < 1024 = 128 px * 8 chunks
    int w2 = chunk >> 3;
    int cc = chunk & 7;
    union { ushort_t u[8]; int4 v; } pk;
#pragma unroll
    for (int j = 0; j < 8; ++j) pk.u[j] = f2bf(tile[(cc * 8 + j) * 129 + w2]);
    *reinterpret_cast<int4*>(xT + (((size_t)(b * 128 + h) * 128 + w2) * 64 + cc * 8)) = pk.v;
  }
}

// Per (b,o): ctx_vec -> kernels (tanh, mean-subtract) -> fold value_w -> A[b][o][tap*64+c] bf16
__global__ void k_gen(const float* __restrict__ xsum,
                      const float* __restrict__ ctx_w, const float* __restrict__ ctx_b,
                      const float* __restrict__ kg_w, const float* __restrict__ kg_b,
                      const float* __restrict__ gamma, const float* __restrict__ value_w,
                      ushort_t* __restrict__ A) {
  __shared__ float xm[64];
  __shared__ float ctxv[16];
  __shared__ float ks_[576];
  __shared__ float red[256];
  __shared__ float vw[4096];
  int b = blockIdx.x >> 6;
  int o = blockIdx.x & 63;
  int tid = threadIdx.x;
  if (tid < 64) xm[tid] = xsum[b * 64 + tid] * (1.f / 16384.f);
#pragma unroll
  for (int p = 0; p < 16; ++p) vw[tid + p * 256] = value_w[tid + p * 256];
  __syncthreads();
  if (tid < 16) {
    float s = ctx_b[tid];
#pragma unroll 8
    for (int c = 0; c < 64; ++c) s += xm[c] * ctx_w[tid * 64 + c];
    ctxv[tid] = s;
  }
  __syncthreads();
  float val[3] = {0.f, 0.f, 0.f};
  float partial = 0.f;
#pragma unroll
  for (int p = 0; p < 3; ++p) {
    int i = tid + p * 256;
    if (i < 576) {
      int n = o * 576 + i;  // kernels_flat index: o*(C*K*K) + c'*9 + tap
      float s = kg_b[n];
      const float* kwp = kg_w + (size_t)n * 16;
#pragma unroll
      for (int j = 0; j < 16; ++j) s += ctxv[j] * kwp[j];
      val[p] = tanhf(s);
      partial += val[p];
    }
  }
  red[tid] = partial;
  __syncthreads();
  for (int s = 128; s > 0; s >>= 1) {
    if (tid < s) red[tid] += red[tid + s];
    __syncthreads();
  }
  float mean = red[0] * (1.f / 576.f);
  float lam = 1.f / (1.f + expf(-gamma[o]));
#pragma unroll
  for (int p = 0; p < 3; ++p) {
    int i = tid + p * 256;
    if (i < 576) ks_[i] = val[p] - lam * mean;  // i = c'*9 + tap
  }
  __syncthreads();
  ushort_t* Ao = A + (size_t)(b * 64 + o) * 576;
#pragma unroll
  for (int p = 0; p < 3; ++p) {
    int f = tid + p * 256;
    if (f < 576) {
      int tap = f >> 6;  // f = tap*64 + c
      int c = f & 63;
      float s = 0.f;
#pragma unroll 8
      for (int cp = 0; cp < 64; ++cp) s += ks_[cp * 9 + tap] * vw[cp * 64 + c];
      Ao[f] = f2bf(s);
    }
  }
}

// Dynamic 3x3 conv via MFMA.
// Block = one batch x (8h x 32w) pixel tile, 4 waves x 16 o each (all 64 o).
// B-fragment reuse: a fragment at absolute LDS row ar feeds up to 3 accumulators
// (kh = 0..2, rr = ar-kh), so ds_read_b128 : MFMA = 120 : 288 per wave (was 144:144).
// grid = 512 = exactly 2 blocks/CU resident (launch_bounds(256,2)) -> no tail round.
__launch_bounds__(256, 2)
__global__ void k_conv(const ushort_t* __restrict__ xT, const ushort_t* __restrict__ A,
                       const float* __restrict__ bias, float* __restrict__ out) {
  // LDS x tile: [10 rows][34 cols][72 ch-padded] bf16 (stride 72 -> 2-way bank alias, free)
  __shared__ __align__(16) ushort_t xs[10 * 34 * 72];
  int bx = blockIdx.x;
  int b = bx >> 6;
  int rem = bx & 63;
  int h0 = (rem >> 2) * 8;
  int w0 = (rem & 3) * 32;
  int tid = threadIdx.x;
  int wave = tid >> 6;
  int lane = tid & 63;
  int n16 = lane & 15;
  int q = lane >> 4;

  // A fragments: A[m=lane&15][k=q*8+j], k ordered f = tap*64 + c; 18 k-steps of 32
  bf16x8 af[18];
  const ushort_t* Ag = A + (size_t)(b * 64 + wave * 16 + n16) * 576 + q * 8;
#pragma unroll
  for (int ks = 0; ks < 18; ++ks)
    af[ks] = *reinterpret_cast<const bf16x8*>(Ag + ks * 32);

  // stage x tile: rows h0-1..h0+8, cols w0-1..w0+32, 64 ch, 16B chunks
  const ushort_t* xb = xT + (size_t)b * 128 * 128 * 64;
#pragma unroll
  for (int it = 0; it < 11; ++it) {
    int chunk = tid + it * 256;
    if (chunk < 2720) {             // 10*34*8
      int lr = chunk / 272;         // 34*8
      int r2 = chunk - lr * 272;
      int lc = r2 >> 3;
      int cc = r2 & 7;
      int hh = h0 - 1 + lr;
      int ww = w0 - 1 + lc;
      int4 v = make_int4(0, 0, 0, 0);
      if (hh >= 0 && hh < 128 && ww >= 0 && ww < 128)
        v = *reinterpret_cast<const int4*>(xb + ((size_t)(hh * 128 + ww) * 64 + cc * 8));
      *reinterpret_cast<int4*>(xs + ((lr * 34 + lc) * 72 + cc * 8)) = v;
    }
  }
  __syncthreads();

  f32x4 acc[16];
#pragma unroll
  for (int i = 0; i < 16; ++i) acc[i] = (f32x4){0.f, 0.f, 0.f, 0.f};

  const ushort_t* xsl = xs + n16 * 72 + q * 8;
#pragma unroll
  for (int ar = 0; ar < 10; ++ar) {
#pragma unroll
    for (int cb = 0; cb < 2; ++cb) {
#pragma unroll
      for (int kw2 = 0; kw2 < 3; ++kw2) {
#pragma unroll
        for (int cq = 0; cq < 2; ++cq) {
          bf16x8 bf = *reinterpret_cast<const bf16x8*>(
              xsl + (ar * 34 + cb * 16 + kw2) * 72 + cq * 32);
#pragma unroll
          for (int kh = 0; kh < 3; ++kh) {
            int rr = ar - kh;            // compile-time: unrolled, pruned
            if (rr >= 0 && rr < 8) {
              acc[rr * 2 + cb] = __builtin_amdgcn_mfma_f32_16x16x32_bf16(
                  af[(kh * 3 + kw2) * 2 + cq], bf, acc[rr * 2 + cb], 0, 0, 0);
            }
          }
        }
      }
    }
  }

  // epilogue: D mapping col(pixel)=lane&15, row(o)=q*4+reg
#pragma unroll
  for (int rr = 0; rr < 8; ++rr) {
#pragma unroll
    for (int cb = 0; cb < 2; ++cb) {
      int nt = rr * 2 + cb;
      int hcur = h0 + rr;
      int wcur = w0 + cb * 16 + n16;
#pragma unroll
      for (int r = 0; r < 4; ++r) {
        int o = wave * 16 + q * 4 + r;
        float v = acc[nt][r] + bias[o];
        v = fmaxf(v, 0.f);
        out[((size_t)(b * 64 + o) * 128 + hcur) * 128 + wcur] = v;
      }
    }
  }
}

extern "C" void kernel_launch(void* const* d_in, const int* in_sizes, int n_in,
                              void* d_out, int out_size, void* d_ws, size_t ws_size,
                              hipStream_t stream) {
  const float* x       = (const float*)d_in[0];
  const float* ctx_w   = (const float*)d_in[1];
  const float* ctx_b   = (const float*)d_in[2];
  const float* kg_w    = (const float*)d_in[3];
  const float* kg_b    = (const float*)d_in[4];
  const float* gamma   = (const float*)d_in[5];
  const float* bias    = (const float*)d_in[6];
  const float* value_w = (const float*)d_in[7];
  float* out = (float*)d_out;

  float* xsum  = (float*)((char*)d_ws + WS_XSUM);
  ushort_t* xT = (ushort_t*)((char*)d_ws + WS_XT);
  ushort_t* A  = (ushort_t*)((char*)d_ws + WS_A);

  k_zero<<<2, 256, 0, stream>>>(xsum);
  k_trans<<<1024, 256, 0, stream>>>(x, xT, xsum);
  k_gen<<<512, 256, 0, stream>>>(xsum, ctx_w, ctx_b, kg_w, kg_b, gamma, value_w, A);
  k_conv<<<512, 256, 0, stream>>>(xT, A, bias, out);
}